// Round 1
// baseline (424.678 us; speedup 1.0000x reference)
//
#include <hip/hip_runtime.h>
#include <cstdint>

typedef unsigned short u16;
typedef __attribute__((ext_vector_type(8))) short short8;
typedef __attribute__((ext_vector_type(4))) float float4v;

#define NTOK 8192
#define HDIM 1024
#define NEXP 8
#define TM 64
#define TN 64
#define BK 32
#define LDSS 40   // LDS row stride in bf16 elems (80B: 16B-aligned, 2-way bank alias only)

__device__ __forceinline__ u16 f2bf(float f) {
    union { float f; uint32_t u; } v; v.f = f;
    uint32_t u = v.u;
    return (u16)((u + 0x7FFFu + ((u >> 16) & 1u)) >> 16);
}

// ---------------- W transpose + bf16 quantize: W[e][k][n] -> Wt[e][n][k] ----------------
__global__ __launch_bounds__(256) void prep_w(const float* __restrict__ w,
                                              u16* __restrict__ wt) {
    __shared__ float tile[32][33];
    const int e  = blockIdx.z;
    const int k0 = blockIdx.x * 32;
    const int n0 = blockIdx.y * 32;
    const int r = threadIdx.x >> 5;   // 0..7
    const int c = threadIdx.x & 31;   // 0..31
    const float* src = w + ((size_t)e << 20) + (size_t)k0 * HDIM + n0;
#pragma unroll
    for (int i = 0; i < 32; i += 8)
        tile[r + i][c] = src[(size_t)(r + i) * HDIM + c];
    __syncthreads();
    u16* dst = wt + ((size_t)e << 20) + (size_t)n0 * HDIM + k0;
#pragma unroll
    for (int i = 0; i < 32; i += 8)
        dst[(size_t)(r + i) * HDIM + c] = f2bf(tile[c][r + i]);
}

// ---------------- router: logits, softmax, top-2, lists; also x -> bf16 ----------------
__global__ __launch_bounds__(256) void router(const float* __restrict__ x,
                                              const float* __restrict__ rw,
                                              u16* __restrict__ x_bf,
                                              float* __restrict__ wt0,
                                              float* __restrict__ wt1,
                                              float* __restrict__ biasv,
                                              int* __restrict__ lists,
                                              int* __restrict__ counts) {
    const int wv = threadIdx.x >> 6;
    const int l  = threadIdx.x & 63;
    const int n  = blockIdx.x * 4 + wv;  // one wave per token
    const float* xr = x + (size_t)n * HDIM;

    float xv[16];
#pragma unroll
    for (int t = 0; t < 16; t++) {
        xv[t] = xr[t * 64 + l];
        x_bf[(size_t)n * HDIM + t * 64 + l] = f2bf(xv[t]);
    }

    float logits[NEXP];
#pragma unroll
    for (int e = 0; e < NEXP; e++) {
        float acc = 0.f;
        const float* rwe = rw + e * HDIM;
#pragma unroll
        for (int t = 0; t < 16; t++) acc += xv[t] * rwe[t * 64 + l];
#pragma unroll
        for (int s = 32; s > 0; s >>= 1) acc += __shfl_xor(acc, s, 64);
        logits[e] = acc;
    }

    if (l == 0) {
        float mx = logits[0];
#pragma unroll
        for (int e = 1; e < NEXP; e++) mx = fmaxf(mx, logits[e]);
        float p[NEXP]; float sum = 0.f;
#pragma unroll
        for (int e = 0; e < NEXP; e++) { p[e] = expf(logits[e] - mx); sum += p[e]; }
        const float inv = 1.f / sum;
#pragma unroll
        for (int e = 0; e < NEXP; e++) p[e] *= inv;
        int e0 = 0;
#pragma unroll
        for (int e = 1; e < NEXP; e++) if (p[e] > p[e0]) e0 = e;  // ties -> lowest idx (matches top_k)
        int e1 = (e0 == 0) ? 1 : 0;
#pragma unroll
        for (int e = 0; e < NEXP; e++) if (e != e0 && p[e] > p[e1]) e1 = e;
        const float p0 = p[e0], p1 = p[e1];
        const float wsum = p0 + p1 + 1e-6f;
        const float w0 = p0 / wsum, w1 = p1 / wsum;
        wt0[n] = w0; wt1[n] = w1;
        biasv[n] = w0 * p0 + w1 * p1;
        int pos0 = atomicAdd(&counts[e0], 1);
        lists[e0 * NTOK + pos0] = n;              // slot 0
        int pos1 = atomicAdd(&counts[e1], 1);
        lists[e1 * NTOK + pos1] = n | 0x10000;    // slot 1
    }
}

// ---------------- grouped GEMM: per-expert gathered X @ Wt, scaled scatter-add ----------------
__global__ __launch_bounds__(256) void moe_gemm(const u16* __restrict__ x_bf,
                                                const u16* __restrict__ wt_bf,
                                                const int* __restrict__ lists,
                                                const int* __restrict__ counts,
                                                const float* __restrict__ wt0,
                                                const float* __restrict__ wt1,
                                                const float* __restrict__ biasv,
                                                float* __restrict__ out) {
    const int e = blockIdx.z;
    const int cnt = counts[e];
    const int tile_m = blockIdx.x * TM;
    if (tile_m >= cnt) return;
    const int tn = blockIdx.y * TN;

    __shared__ u16 lA[TM * LDSS];
    __shared__ u16 lB[TN * LDSS];
    __shared__ int   toks[TM];
    __shared__ float wgt[TM];
    __shared__ float bia[TM];

    const int t = threadIdx.x;
    if (t < TM) {
        const int idx = tile_m + t;
        int tok = 0; float w = 0.f, b = 0.f;
        if (idx < cnt) {
            const int entry = lists[e * NTOK + idx];
            tok = entry & 0xFFFF;
            const int slot = entry >> 16;
            w = slot ? wt1[tok] : wt0[tok];
            b = slot ? 0.f : biasv[tok];
        }
        toks[t] = tok; wgt[t] = w; bia[t] = b;
    }
    __syncthreads();

    const int row = t >> 2;          // 0..63
    const int kq  = (t & 3) * 8;     // 0,8,16,24 (bf16 elems)
    const int tokr = toks[row];
    const u16* abase = x_bf + (size_t)tokr * HDIM + kq;
    const u16* bbase = wt_bf + ((size_t)e << 20) + (size_t)(tn + row) * HDIM + kq;

    const int wv = t >> 6;     // wave 0..3
    const int l  = t & 63;
    const int a_off = (wv * 16 + (l & 15)) * LDSS + (l >> 4) * 8;

    float4v acc[4];
#pragma unroll
    for (int j = 0; j < 4; j++) { float4v z = {0.f, 0.f, 0.f, 0.f}; acc[j] = z; }

    for (int k0 = 0; k0 < HDIM; k0 += BK) {
        const uint4 av = *(const uint4*)(abase + k0);
        const uint4 bv = *(const uint4*)(bbase + k0);
        __syncthreads();  // previous iteration's LDS reads done
        *(uint4*)&lA[row * LDSS + kq] = av;
        *(uint4*)&lB[row * LDSS + kq] = bv;
        __syncthreads();
        const short8 a = *(const short8*)&lA[a_off];
#pragma unroll
        for (int j = 0; j < 4; j++) {
            const short8 b = *(const short8*)&lB[(j * 16 + (l & 15)) * LDSS + (l >> 4) * 8];
            acc[j] = __builtin_amdgcn_mfma_f32_16x16x32_bf16(a, b, acc[j], 0, 0, 0);
        }
    }

    // epilogue: out[tok][h] += w * acc (+ bias once, from slot-0 contribution)
#pragma unroll
    for (int j = 0; j < 4; j++) {
#pragma unroll
        for (int r = 0; r < 4; r++) {
            const int m_local = wv * 16 + (l >> 4) * 4 + r;
            if (tile_m + m_local < cnt) {
                const int tok = toks[m_local];
                const int h = tn + j * 16 + (l & 15);
                const float val = acc[j][r] * wgt[m_local] + bia[m_local];
                atomicAdd(&out[(size_t)tok * HDIM + h], val);
            }
        }
    }
}

extern "C" void kernel_launch(void* const* d_in, const int* in_sizes, int n_in,
                              void* d_out, int out_size, void* d_ws, size_t ws_size,
                              hipStream_t stream) {
    const float* x  = (const float*)d_in[0];   // [4,2048,1024]
    const float* rw = (const float*)d_in[1];   // [8,1024]
    const float* ew = (const float*)d_in[2];   // [8,1024,1024]
    float* out = (float*)d_out;

    char* ws = (char*)d_ws;
    u16*   x_bf   = (u16*)ws;                          // 16 MiB
    u16*   w_bf   = (u16*)(ws + 16777216);             // 16 MiB
    float* wt0    = (float*)(ws + 33554432);           // 32 KiB
    float* wt1    = (float*)(ws + 33587200);           // 32 KiB
    float* biasv  = (float*)(ws + 33619968);           // 32 KiB
    int*   lists  = (int*)(ws + 33652736);             // 256 KiB
    int*   counts = (int*)(ws + 33914880);             // 32 B

    hipMemsetAsync(d_out, 0, (size_t)out_size * sizeof(float), stream);
    hipMemsetAsync(counts, 0, NEXP * sizeof(int), stream);

    prep_w<<<dim3(32, 32, NEXP), 256, 0, stream>>>(ew, w_bf);
    router<<<NTOK / 4, 256, 0, stream>>>(x, rw, x_bf, wt0, wt1, biasv, lists, counts);
    moe_gemm<<<dim3(NTOK / TM, HDIM / TN, NEXP), 256, 0, stream>>>(
        x_bf, w_bf, lists, counts, wt0, wt1, biasv, out);
}

// Round 2
// 241.733 us; speedup vs baseline: 1.7568x; 1.7568x over previous
//
#include <hip/hip_runtime.h>
#include <cstdint>

typedef unsigned short u16;
typedef __attribute__((ext_vector_type(8))) short short8;
typedef __attribute__((ext_vector_type(4))) float float4v;

#define NTOK 8192
#define HDIM 1024
#define NEXP 8
#define TM 64
#define TN 64
#define BK 64
#define LDSS 72   // LDS row stride in bf16 elems (144B, 16B-aligned; 2-way bank alias = free)

__device__ __forceinline__ u16 f2bf(float f) {
    union { float f; uint32_t u; } v; v.f = f;
    uint32_t u = v.u;
    return (u16)((u + 0x7FFFu + ((u >> 16) & 1u)) >> 16);
}

// ---------------- W transpose + bf16 quantize: W[e][k][n] -> Wt[e][n][k] ----------------
__global__ __launch_bounds__(256) void prep_w(const float* __restrict__ w,
                                              u16* __restrict__ wt) {
    __shared__ float tile[32][33];
    const int e  = blockIdx.z;
    const int k0 = blockIdx.x * 32;
    const int n0 = blockIdx.y * 32;
    const int r = threadIdx.x >> 5;   // 0..7
    const int c = threadIdx.x & 31;   // 0..31
    const float* src = w + ((size_t)e << 20) + (size_t)k0 * HDIM + n0;
#pragma unroll
    for (int i = 0; i < 32; i += 8)
        tile[r + i][c] = src[(size_t)(r + i) * HDIM + c];
    __syncthreads();
    u16* dst = wt + ((size_t)e << 20) + (size_t)n0 * HDIM + k0;
#pragma unroll
    for (int i = 0; i < 32; i += 8)
        dst[(size_t)(r + i) * HDIM + c] = f2bf(tile[c][r + i]);
}

// ---------------- router: logits, softmax, top-2 -> per-token arrays (NO atomics) ------
__global__ __launch_bounds__(256) void router(const float* __restrict__ x,
                                              const float* __restrict__ rw,
                                              u16* __restrict__ x_bf,
                                              float* __restrict__ wt0,
                                              float* __restrict__ wt1,
                                              float* __restrict__ biasv,
                                              int* __restrict__ sel) {
    const int wv = threadIdx.x >> 6;
    const int l  = threadIdx.x & 63;
    const int n  = blockIdx.x * 4 + wv;  // one wave per token
    const float* xr = x + (size_t)n * HDIM;

    float xv[16];
#pragma unroll
    for (int t = 0; t < 16; t++) {
        xv[t] = xr[t * 64 + l];
        x_bf[(size_t)n * HDIM + t * 64 + l] = f2bf(xv[t]);
    }

    float logits[NEXP];
#pragma unroll
    for (int e = 0; e < NEXP; e++) {
        float acc = 0.f;
        const float* rwe = rw + e * HDIM;
#pragma unroll
        for (int t = 0; t < 16; t++) acc += xv[t] * rwe[t * 64 + l];
#pragma unroll
        for (int s = 32; s > 0; s >>= 1) acc += __shfl_xor(acc, s, 64);
        logits[e] = acc;
    }

    if (l == 0) {
        float mx = logits[0];
#pragma unroll
        for (int e = 1; e < NEXP; e++) mx = fmaxf(mx, logits[e]);
        float p[NEXP]; float sum = 0.f;
#pragma unroll
        for (int e = 0; e < NEXP; e++) { p[e] = expf(logits[e] - mx); sum += p[e]; }
        const float inv = 1.f / sum;
#pragma unroll
        for (int e = 0; e < NEXP; e++) p[e] *= inv;
        int e0 = 0;
#pragma unroll
        for (int e = 1; e < NEXP; e++) if (p[e] > p[e0]) e0 = e;  // ties -> lowest idx (matches top_k)
        int e1 = (e0 == 0) ? 1 : 0;
#pragma unroll
        for (int e = 0; e < NEXP; e++) if (e != e0 && p[e] > p[e1]) e1 = e;
        const float p0 = p[e0], p1 = p[e1];
        const float wsum = p0 + p1 + 1e-6f;
        const float w0 = p0 / wsum, w1 = p1 / wsum;
        wt0[n] = w0; wt1[n] = w1;
        biasv[n] = w0 * p0 + w1 * p1;
        sel[n] = e0 | (e1 << 8);
    }
}

// ---------------- list build: 1 block per expert, ballot-compaction, no global atomics --
__global__ __launch_bounds__(256) void build_lists(const int* __restrict__ sel,
                                                   int* __restrict__ lists,
                                                   int* __restrict__ counts) {
    const int e = blockIdx.x;
    __shared__ int base;
    __shared__ int wsum[4];
    if (threadIdx.x == 0) base = 0;
    const int wv = threadIdx.x >> 6;
    const int l  = threadIdx.x & 63;
    __syncthreads();
    for (int n0 = 0; n0 < NTOK; n0 += 256) {
        const int n = n0 + threadIdx.x;
        const int s = sel[n];
        int slot = -1;
        if ((s & 0xFF) == e) slot = 0;
        else if ((s >> 8) == e) slot = 1;
        const unsigned long long bal = __ballot(slot >= 0);
        const int prefix = __popcll(bal & ((1ULL << l) - 1ULL));
        if (l == 0) wsum[wv] = __popcll(bal);
        __syncthreads();                 // wsum visible; prev base update visible
        int woff = 0;
#pragma unroll
        for (int i = 0; i < 4; i++) woff += (i < wv) ? wsum[i] : 0;
        const int total = wsum[0] + wsum[1] + wsum[2] + wsum[3];
        if (slot >= 0) lists[e * NTOK + base + woff + prefix] = n | (slot << 16);
        __syncthreads();                 // all reads of base/wsum done
        if (threadIdx.x == 0) base += total;
    }
    __syncthreads();
    if (threadIdx.x == 0) counts[e] = base;
}

// ---------------- grouped GEMM: per-expert gathered X @ Wt, scaled scatter-add ----------------
__global__ __launch_bounds__(256) void moe_gemm(const u16* __restrict__ x_bf,
                                                const u16* __restrict__ wt_bf,
                                                const int* __restrict__ lists,
                                                const int* __restrict__ counts,
                                                const float* __restrict__ wt0,
                                                const float* __restrict__ wt1,
                                                const float* __restrict__ biasv,
                                                float* __restrict__ out) {
    const int e = blockIdx.z;
    const int cnt = counts[e];
    const int tile_m = blockIdx.x * TM;
    if (tile_m >= cnt) return;
    const int tn = blockIdx.y * TN;

    __shared__ u16 lA[TM * LDSS];
    __shared__ u16 lB[TN * LDSS];
    __shared__ int   toks[TM];
    __shared__ float wgt[TM];
    __shared__ float bia[TM];

    const int t = threadIdx.x;
    if (t < TM) {
        const int idx = tile_m + t;
        int tok = 0; float w = 0.f, b = 0.f;
        if (idx < cnt) {
            const int entry = lists[e * NTOK + idx];
            tok = entry & 0xFFFF;
            const int slot = entry >> 16;
            w = slot ? wt1[tok] : wt0[tok];
            b = slot ? 0.f : biasv[tok];
        }
        toks[t] = tok; wgt[t] = w; bia[t] = b;
    }
    __syncthreads();

    const int row = t >> 2;          // 0..63
    const int kq  = (t & 3) * 16;    // 0,16,32,48 (bf16 elems)
    const int tokr = toks[row];
    const u16* abase = x_bf + (size_t)tokr * HDIM + kq;
    const u16* bbase = wt_bf + ((size_t)e << 20) + (size_t)(tn + row) * HDIM + kq;

    const int wv = t >> 6;     // wave 0..3
    const int l  = t & 63;
    const int a_row = (wv * 16 + (l & 15)) * LDSS + (l >> 4) * 8;

    float4v acc[4];
#pragma unroll
    for (int j = 0; j < 4; j++) { float4v z = {0.f, 0.f, 0.f, 0.f}; acc[j] = z; }

    for (int k0 = 0; k0 < HDIM; k0 += BK) {
        const uint4 av0 = *(const uint4*)(abase + k0);
        const uint4 av1 = *(const uint4*)(abase + k0 + 8);
        const uint4 bv0 = *(const uint4*)(bbase + k0);
        const uint4 bv1 = *(const uint4*)(bbase + k0 + 8);
        __syncthreads();  // previous iteration's LDS reads done
        *(uint4*)&lA[row * LDSS + kq]     = av0;
        *(uint4*)&lA[row * LDSS + kq + 8] = av1;
        *(uint4*)&lB[row * LDSS + kq]     = bv0;
        *(uint4*)&lB[row * LDSS + kq + 8] = bv1;
        __syncthreads();
#pragma unroll
        for (int kk = 0; kk < BK; kk += 32) {
            const short8 a = *(const short8*)&lA[a_row + kk];
#pragma unroll
            for (int j = 0; j < 4; j++) {
                const short8 b = *(const short8*)&lB[(j * 16 + (l & 15)) * LDSS + kk + (l >> 4) * 8];
                acc[j] = __builtin_amdgcn_mfma_f32_16x16x32_bf16(a, b, acc[j], 0, 0, 0);
            }
        }
    }

    // epilogue: out[tok][h] += w * acc (+ bias once, from slot-0 contribution)
#pragma unroll
    for (int j = 0; j < 4; j++) {
#pragma unroll
        for (int r = 0; r < 4; r++) {
            const int m_local = wv * 16 + (l >> 4) * 4 + r;
            if (tile_m + m_local < cnt) {
                const int tok = toks[m_local];
                const int h = tn + j * 16 + (l & 15);
                const float val = acc[j][r] * wgt[m_local] + bia[m_local];
                atomicAdd(&out[(size_t)tok * HDIM + h], val);
            }
        }
    }
}

extern "C" void kernel_launch(void* const* d_in, const int* in_sizes, int n_in,
                              void* d_out, int out_size, void* d_ws, size_t ws_size,
                              hipStream_t stream) {
    const float* x  = (const float*)d_in[0];   // [4,2048,1024]
    const float* rw = (const float*)d_in[1];   // [8,1024]
    const float* ew = (const float*)d_in[2];   // [8,1024,1024]
    float* out = (float*)d_out;

    char* ws = (char*)d_ws;
    u16*   x_bf   = (u16*)ws;                          // 16 MiB
    u16*   w_bf   = (u16*)(ws + 16777216);             // 16 MiB
    float* wt0    = (float*)(ws + 33554432);           // 32 KiB
    float* wt1    = (float*)(ws + 33587200);           // 32 KiB
    float* biasv  = (float*)(ws + 33619968);           // 32 KiB
    int*   sel    = (int*)(ws + 33652736);             // 32 KiB
    int*   lists  = (int*)(ws + 33685504);             // 256 KiB
    int*   counts = (int*)(ws + 33947648);             // 32 B

    hipMemsetAsync(d_out, 0, (size_t)out_size * sizeof(float), stream);

    prep_w<<<dim3(32, 32, NEXP), 256, 0, stream>>>(ew, w_bf);
    router<<<NTOK / 4, 256, 0, stream>>>(x, rw, x_bf, wt0, wt1, biasv, sel);
    build_lists<<<NEXP, 256, 0, stream>>>(sel, lists, counts);
    moe_gemm<<<dim3(NTOK / TM, HDIM / TN, NEXP), 256, 0, stream>>>(
        x_bf, w_bf, lists, counts, wt0, wt1, biasv, out);
}

// Round 3
// 236.993 us; speedup vs baseline: 1.7919x; 1.0200x over previous
//
#include <hip/hip_runtime.h>
#include <cstdint>

typedef unsigned short u16;
typedef __attribute__((ext_vector_type(8))) short short8;
typedef __attribute__((ext_vector_type(4))) float float4v;

#define NTOK 8192
#define HDIM 1024
#define NEXP 8
#define TM 128
#define TN 128
#define BK 32

__device__ __forceinline__ u16 f2bf(float f) {
    union { float f; uint32_t u; } v; v.f = f;
    uint32_t u = v.u;
    return (u16)((u + 0x7FFFu + ((u >> 16) & 1u)) >> 16);
}

// async global->LDS, 16B per lane; LDS dest = wave-uniform base + lane*16
__device__ __forceinline__ void gll16(const u16* g, u16* l) {
    __builtin_amdgcn_global_load_lds(
        (const __attribute__((address_space(1))) uint32_t*)g,
        (__attribute__((address_space(3))) uint32_t*)l,
        16, 0, 0);
}

// ---------------- W transpose + bf16 quantize: W[e][k][n] -> Wt[e][n][k] ----------------
__global__ __launch_bounds__(256) void prep_w(const float* __restrict__ w,
                                              u16* __restrict__ wt) {
    __shared__ float tile[32][33];
    const int e  = blockIdx.z;
    const int k0 = blockIdx.x * 32;
    const int n0 = blockIdx.y * 32;
    const int r = threadIdx.x >> 3;        // 0..31
    const int c = (threadIdx.x & 7) * 4;   // 0,4,...,28
    const float4 v = *(const float4*)(w + ((size_t)e << 20) + (size_t)(k0 + r) * HDIM + n0 + c);
    tile[r][c] = v.x; tile[r][c+1] = v.y; tile[r][c+2] = v.z; tile[r][c+3] = v.w;
    __syncthreads();
    ushort4 o;
    o.x = f2bf(tile[c][r]); o.y = f2bf(tile[c+1][r]);
    o.z = f2bf(tile[c+2][r]); o.w = f2bf(tile[c+3][r]);
    *(ushort4*)(wt + ((size_t)e << 20) + (size_t)(n0 + r) * HDIM + k0 + c) = o;
}

// ---------------- router: logits, softmax, top-2 -> per-token arrays (NO atomics) ------
__global__ __launch_bounds__(256) void router(const float* __restrict__ x,
                                              const float* __restrict__ rw,
                                              u16* __restrict__ x_bf,
                                              float* __restrict__ wt0,
                                              float* __restrict__ wt1,
                                              float* __restrict__ biasv,
                                              int* __restrict__ sel) {
    const int wv = threadIdx.x >> 6;
    const int l  = threadIdx.x & 63;
    const int n  = blockIdx.x * 4 + wv;  // one wave per token
    const float4* xr = (const float4*)(x + (size_t)n * HDIM);
    ushort4* xo = (ushort4*)(x_bf + (size_t)n * HDIM);

    float4 xv[4];
#pragma unroll
    for (int t = 0; t < 4; t++) {
        xv[t] = xr[t * 64 + l];
        ushort4 p;
        p.x = f2bf(xv[t].x); p.y = f2bf(xv[t].y);
        p.z = f2bf(xv[t].z); p.w = f2bf(xv[t].w);
        xo[t * 64 + l] = p;
    }

    float logits[NEXP];
#pragma unroll
    for (int e = 0; e < NEXP; e++) {
        const float4* rwe = (const float4*)(rw + e * HDIM);
        float acc = 0.f;
#pragma unroll
        for (int t = 0; t < 4; t++) {
            const float4 r = rwe[t * 64 + l];
            acc += xv[t].x * r.x + xv[t].y * r.y + xv[t].z * r.z + xv[t].w * r.w;
        }
#pragma unroll
        for (int s = 32; s > 0; s >>= 1) acc += __shfl_xor(acc, s, 64);
        logits[e] = acc;
    }

    if (l == 0) {
        float mx = logits[0];
#pragma unroll
        for (int e = 1; e < NEXP; e++) mx = fmaxf(mx, logits[e]);
        float p[NEXP]; float sum = 0.f;
#pragma unroll
        for (int e = 0; e < NEXP; e++) { p[e] = expf(logits[e] - mx); sum += p[e]; }
        const float inv = 1.f / sum;
#pragma unroll
        for (int e = 0; e < NEXP; e++) p[e] *= inv;
        int e0 = 0;
#pragma unroll
        for (int e = 1; e < NEXP; e++) if (p[e] > p[e0]) e0 = e;  // ties -> lowest idx (matches top_k)
        int e1 = (e0 == 0) ? 1 : 0;
#pragma unroll
        for (int e = 0; e < NEXP; e++) if (e != e0 && p[e] > p[e1]) e1 = e;
        const float p0 = p[e0], p1 = p[e1];
        const float wsum = p0 + p1 + 1e-6f;
        const float w0 = p0 / wsum, w1 = p1 / wsum;
        wt0[n] = w0; wt1[n] = w1;
        biasv[n] = w0 * p0 + w1 * p1;
        sel[n] = e0 | (e1 << 8);
    }
}

// ---------------- list build: 32 blocks, ballot + 1 atomic per (block,expert) ----------
// List order is irrelevant (epilogue is a scatter-add), so cross-block order is free.
__global__ __launch_bounds__(256) void build_lists(const int* __restrict__ sel,
                                                   int* __restrict__ lists,
                                                   int* __restrict__ counts) {
    const int n  = blockIdx.x * 256 + threadIdx.x;
    const int wv = threadIdx.x >> 6;
    const int l  = threadIdx.x & 63;
    const int s  = sel[n];
    const int e0 = s & 0xFF, e1 = s >> 8;
    __shared__ int wcnt[NEXP][4];
    __shared__ int ebase[NEXP];
    int pf0 = 0, pf1 = 0;
    const unsigned long long ltmask = (1ULL << l) - 1ULL;
#pragma unroll
    for (int e = 0; e < NEXP; e++) {
        const int slot = (e0 == e) ? 0 : ((e1 == e) ? 1 : -1);
        const unsigned long long bal = __ballot(slot >= 0);
        const int pf = __popcll(bal & ltmask);
        if (slot == 0) pf0 = pf;
        if (slot == 1) pf1 = pf;
        if (l == 0) wcnt[e][wv] = __popcll(bal);
    }
    __syncthreads();
    if (threadIdx.x < NEXP) {
        const int e = threadIdx.x;
        const int tot = wcnt[e][0] + wcnt[e][1] + wcnt[e][2] + wcnt[e][3];
        ebase[e] = atomicAdd(&counts[e * 16], tot);   // counters 64B apart
    }
    __syncthreads();
    int off0 = ebase[e0], off1 = ebase[e1];
#pragma unroll
    for (int i = 0; i < 4; i++) {
        off0 += (i < wv) ? wcnt[e0][i] : 0;
        off1 += (i < wv) ? wcnt[e1][i] : 0;
    }
    lists[e0 * NTOK + off0 + pf0] = n;              // slot 0
    lists[e1 * NTOK + off1 + pf1] = n | 0x10000;    // slot 1
}

// ---------------- grouped GEMM: 128x128 tile, global_load_lds staging ----------------
__global__ __launch_bounds__(256) void moe_gemm(const u16* __restrict__ x_bf,
                                                const u16* __restrict__ wt_bf,
                                                const int* __restrict__ lists,
                                                const int* __restrict__ counts,
                                                const float* __restrict__ wt0,
                                                const float* __restrict__ wt1,
                                                const float* __restrict__ biasv,
                                                float* __restrict__ out) {
    const int e = blockIdx.z;
    const int cnt = counts[e * 16];
    const int tile_m = blockIdx.x * TM;
    if (tile_m >= cnt) return;
    const int tn = blockIdx.y * TN;

    __shared__ u16 lA[TM * BK];   // 8 KB, unpadded [row][32] (global_load_lds layout)
    __shared__ u16 lB[TN * BK];   // 8 KB
    __shared__ int   toks[TM];
    __shared__ float wgt[TM];
    __shared__ float bia[TM];

    const int t  = threadIdx.x;
    const int wv = t >> 6;
    const int l  = t & 63;

    if (t < TM) {
        const int idx = tile_m + t;
        int tok = 0; float w = 0.f, b = 0.f;
        if (idx < cnt) {
            const int entry = lists[e * NTOK + idx];
            tok = entry & 0xFFFF;
            const int slot = entry >> 16;
            w = slot ? wt1[tok] : wt0[tok];
            b = slot ? 0.f : biasv[tok];
        }
        toks[t] = tok; wgt[t] = w; bia[t] = b;
    }
    __syncthreads();

    // staging: chunk c (0..7) covers rows [16c,16c+16); lane l -> row 16c+(l>>2), k (l&3)*8
    const int c0 = wv * 2, c1 = wv * 2 + 1;
    const int rs0 = c0 * 16 + (l >> 2);
    const int rs1 = c1 * 16 + (l >> 2);
    const int koff = (l & 3) * 8;
    const u16* pA0 = x_bf + (size_t)toks[rs0] * HDIM + koff;
    const u16* pA1 = x_bf + (size_t)toks[rs1] * HDIM + koff;
    const u16* pB0 = wt_bf + ((size_t)e << 20) + (size_t)(tn + rs0) * HDIM + koff;
    const u16* pB1 = wt_bf + ((size_t)e << 20) + (size_t)(tn + rs1) * HDIM + koff;
    u16* qA0 = lA + c0 * 512;   // 1 KB chunks, wave-uniform
    u16* qA1 = lA + c1 * 512;
    u16* qB0 = lB + c0 * 512;
    u16* qB1 = lB + c1 * 512;

    // compute: wave -> 64x64 subtile at (wm, wn)
    const int wm = (wv & 1) * 64;
    const int wn = (wv >> 1) * 64;
    const int fm = l & 15;
    const int fk = (l >> 4) * 8;

    float4v acc[4][4];
#pragma unroll
    for (int i = 0; i < 4; i++)
#pragma unroll
        for (int j = 0; j < 4; j++) { float4v z = {0.f, 0.f, 0.f, 0.f}; acc[i][j] = z; }

    for (int k0 = 0; k0 < HDIM; k0 += BK) {
        __syncthreads();                 // prior iteration's ds_reads complete
        gll16(pA0 + k0, qA0);
        gll16(pA1 + k0, qA1);
        gll16(pB0 + k0, qB0);
        gll16(pB1 + k0, qB1);
        __syncthreads();                 // compiler drains vmcnt before s_barrier

        short8 af[4], bf[4];
#pragma unroll
        for (int mf = 0; mf < 4; mf++)
            af[mf] = *(const short8*)&lA[(wm + mf * 16 + fm) * BK + fk];
#pragma unroll
        for (int nf = 0; nf < 4; nf++)
            bf[nf] = *(const short8*)&lB[(wn + nf * 16 + fm) * BK + fk];
#pragma unroll
        for (int mf = 0; mf < 4; mf++)
#pragma unroll
            for (int nf = 0; nf < 4; nf++)
                acc[mf][nf] = __builtin_amdgcn_mfma_f32_16x16x32_bf16(af[mf], bf[nf], acc[mf][nf], 0, 0, 0);
    }

    // epilogue: out[tok][h] += w * acc (+ bias once, from slot-0 contribution)
#pragma unroll
    for (int mf = 0; mf < 4; mf++) {
#pragma unroll
        for (int r = 0; r < 4; r++) {
            const int m_local = wm + mf * 16 + (l >> 4) * 4 + r;
            if (tile_m + m_local < cnt) {
                const int tok = toks[m_local];
                const float w = wgt[m_local], b = bia[m_local];
#pragma unroll
                for (int nf = 0; nf < 4; nf++) {
                    const int h = tn + wn + nf * 16 + fm;
                    atomicAdd(&out[(size_t)tok * HDIM + h], acc[mf][nf][r] * w + b * (nf == 0 ? 1.f : 0.f) + ((nf != 0) ? b : 0.f));
                }
            }
        }
    }
}

extern "C" void kernel_launch(void* const* d_in, const int* in_sizes, int n_in,
                              void* d_out, int out_size, void* d_ws, size_t ws_size,
                              hipStream_t stream) {
    const float* x  = (const float*)d_in[0];   // [4,2048,1024]
    const float* rw = (const float*)d_in[1];   // [8,1024]
    const float* ew = (const float*)d_in[2];   // [8,1024,1024]
    float* out = (float*)d_out;

    char* ws = (char*)d_ws;
    u16*   x_bf   = (u16*)ws;                          // 16 MiB
    u16*   w_bf   = (u16*)(ws + 16777216);             // 16 MiB
    float* wt0    = (float*)(ws + 33554432);           // 32 KiB
    float* wt1    = (float*)(ws + 33587200);           // 32 KiB
    float* biasv  = (float*)(ws + 33619968);           // 32 KiB
    int*   sel    = (int*)(ws + 33652736);             // 32 KiB
    int*   lists  = (int*)(ws + 33685504);             // 256 KiB
    int*   counts = (int*)(ws + 33947648);             // 512 B (8 counters, 64B apart)

    hipMemsetAsync(d_out, 0, (size_t)out_size * sizeof(float), stream);
    hipMemsetAsync(counts, 0, NEXP * 16 * sizeof(int), stream);

    prep_w<<<dim3(32, 32, NEXP), 256, 0, stream>>>(ew, w_bf);
    router<<<NTOK / 4, 256, 0, stream>>>(x, rw, x_bf, wt0, wt1, biasv, sel);
    build_lists<<<NTOK / 256, 256, 0, stream>>>(sel, lists, counts);
    moe_gemm<<<dim3(NTOK / TM, HDIM / TN, NEXP), 256, 0, stream>>>(
        x_bf, w_bf, lists, counts, wt0, wt1, biasv, out);
}

// Round 4
// 230.344 us; speedup vs baseline: 1.8437x; 1.0289x over previous
//
#include <hip/hip_runtime.h>
#include <cstdint>

typedef unsigned short u16;
typedef __attribute__((ext_vector_type(8))) short short8;
typedef __attribute__((ext_vector_type(4))) float float4v;

#define NTOK 8192
#define HDIM 1024
#define NEXP 8
#define TM 128
#define TN 128
#define BK 32
#define MAXT 136   // max m-tiles over all experts: 16384/128 + 8 rounding partials

__device__ __forceinline__ u16 f2bf(float f) {
    union { float f; uint32_t u; } v; v.f = f;
    uint32_t u = v.u;
    return (u16)((u + 0x7FFFu + ((u >> 16) & 1u)) >> 16);
}

// async global->LDS, 16B per lane; LDS dest = wave-uniform base + lane*16
__device__ __forceinline__ void gll16(const u16* g, u16* l) {
    __builtin_amdgcn_global_load_lds(
        (const __attribute__((address_space(1))) uint32_t*)g,
        (__attribute__((address_space(3))) uint32_t*)l,
        16, 0, 0);
}

// ---------------- W transpose + bf16 quantize: W[e][k][n] -> Wt[e][n][k] ----------------
__global__ __launch_bounds__(256) void prep_w(const float* __restrict__ w,
                                              u16* __restrict__ wt) {
    __shared__ float tile[32][33];
    const int e  = blockIdx.z;
    const int k0 = blockIdx.x * 32;
    const int n0 = blockIdx.y * 32;
    const int r = threadIdx.x >> 3;        // 0..31
    const int c = (threadIdx.x & 7) * 4;   // 0,4,...,28
    const float4 v = *(const float4*)(w + ((size_t)e << 20) + (size_t)(k0 + r) * HDIM + n0 + c);
    tile[r][c] = v.x; tile[r][c+1] = v.y; tile[r][c+2] = v.z; tile[r][c+3] = v.w;
    __syncthreads();
    ushort4 o;
    o.x = f2bf(tile[c][r]); o.y = f2bf(tile[c+1][r]);
    o.z = f2bf(tile[c+2][r]); o.w = f2bf(tile[c+3][r]);
    *(ushort4*)(wt + ((size_t)e << 20) + (size_t)(n0 + r) * HDIM + k0 + c) = o;
}

// ---------------- router: logits, softmax, top-2 -> per-token arrays (NO atomics) ------
__global__ __launch_bounds__(256) void router(const float* __restrict__ x,
                                              const float* __restrict__ rw,
                                              u16* __restrict__ x_bf,
                                              float* __restrict__ wt0,
                                              float* __restrict__ wt1,
                                              float* __restrict__ biasv,
                                              int* __restrict__ sel) {
    const int wv = threadIdx.x >> 6;
    const int l  = threadIdx.x & 63;
    const int n  = blockIdx.x * 4 + wv;  // one wave per token
    const float4* xr = (const float4*)(x + (size_t)n * HDIM);
    ushort4* xo = (ushort4*)(x_bf + (size_t)n * HDIM);

    float4 xv[4];
#pragma unroll
    for (int t = 0; t < 4; t++) {
        xv[t] = xr[t * 64 + l];
        ushort4 p;
        p.x = f2bf(xv[t].x); p.y = f2bf(xv[t].y);
        p.z = f2bf(xv[t].z); p.w = f2bf(xv[t].w);
        xo[t * 64 + l] = p;
    }

    float logits[NEXP];
#pragma unroll
    for (int e = 0; e < NEXP; e++) {
        const float4* rwe = (const float4*)(rw + e * HDIM);
        float acc = 0.f;
#pragma unroll
        for (int t = 0; t < 4; t++) {
            const float4 r = rwe[t * 64 + l];
            acc += xv[t].x * r.x + xv[t].y * r.y + xv[t].z * r.z + xv[t].w * r.w;
        }
#pragma unroll
        for (int s = 32; s > 0; s >>= 1) acc += __shfl_xor(acc, s, 64);
        logits[e] = acc;
    }

    if (l == 0) {
        float mx = logits[0];
#pragma unroll
        for (int e = 1; e < NEXP; e++) mx = fmaxf(mx, logits[e]);
        float p[NEXP]; float sum = 0.f;
#pragma unroll
        for (int e = 0; e < NEXP; e++) { p[e] = expf(logits[e] - mx); sum += p[e]; }
        const float inv = 1.f / sum;
#pragma unroll
        for (int e = 0; e < NEXP; e++) p[e] *= inv;
        int e0 = 0;
#pragma unroll
        for (int e = 1; e < NEXP; e++) if (p[e] > p[e0]) e0 = e;  // ties -> lowest idx (matches top_k)
        int e1 = (e0 == 0) ? 1 : 0;
#pragma unroll
        for (int e = 0; e < NEXP; e++) if (e != e0 && p[e] > p[e1]) e1 = e;
        const float p0 = p[e0], p1 = p[e1];
        const float wsum = p0 + p1 + 1e-6f;
        const float w0 = p0 / wsum, w1 = p1 / wsum;
        wt0[n] = w0; wt1[n] = w1;
        biasv[n] = w0 * p0 + w1 * p1;
        sel[n] = e0 | (e1 << 8);
    }
}

// ---------------- list build: 32 blocks, ballot + 1 atomic per (block,expert) ----------
__global__ __launch_bounds__(256) void build_lists(const int* __restrict__ sel,
                                                   int* __restrict__ lists,
                                                   int* __restrict__ counts) {
    const int n  = blockIdx.x * 256 + threadIdx.x;
    const int wv = threadIdx.x >> 6;
    const int l  = threadIdx.x & 63;
    const int s  = sel[n];
    const int e0 = s & 0xFF, e1 = s >> 8;
    __shared__ int wcnt[NEXP][4];
    __shared__ int ebase[NEXP];
    int pf0 = 0, pf1 = 0;
    const unsigned long long ltmask = (1ULL << l) - 1ULL;
#pragma unroll
    for (int e = 0; e < NEXP; e++) {
        const int slot = (e0 == e) ? 0 : ((e1 == e) ? 1 : -1);
        const unsigned long long bal = __ballot(slot >= 0);
        const int pf = __popcll(bal & ltmask);
        if (slot == 0) pf0 = pf;
        if (slot == 1) pf1 = pf;
        if (l == 0) wcnt[e][wv] = __popcll(bal);
    }
    __syncthreads();
    if (threadIdx.x < NEXP) {
        const int e = threadIdx.x;
        const int tot = wcnt[e][0] + wcnt[e][1] + wcnt[e][2] + wcnt[e][3];
        ebase[e] = atomicAdd(&counts[e * 16], tot);   // counters 64B apart
    }
    __syncthreads();
    int off0 = ebase[e0], off1 = ebase[e1];
#pragma unroll
    for (int i = 0; i < 4; i++) {
        off0 += (i < wv) ? wcnt[e0][i] : 0;
        off1 += (i < wv) ? wcnt[e1][i] : 0;
    }
    lists[e0 * NTOK + off0 + pf0] = n;              // slot 0
    lists[e1 * NTOK + off1 + pf1] = n | 0x10000;    // slot 1
}

// ---------------- tile planner: dense (expert, m-tile) map so the GEMM grid has no holes
__global__ __launch_bounds__(64) void plan_tiles(const int* __restrict__ counts,
                                                 int* __restrict__ tmap) {
    if (threadIdx.x == 0) {
        int idx = 0;
        for (int e = 0; e < NEXP; e++) {
            const int nt = (counts[e * 16] + TM - 1) / TM;
            for (int m = 0; m < nt; m++) tmap[idx++] = (e << 16) | m;
        }
        for (int i = idx; i < MAXT; i++) tmap[i] = -1;
    }
}

// ---------------- grouped GEMM: 128x128 tile, global_load_lds staging, dense grid ------
__global__ __launch_bounds__(256) void moe_gemm(const u16* __restrict__ x_bf,
                                                const u16* __restrict__ wt_bf,
                                                const int* __restrict__ lists,
                                                const int* __restrict__ counts,
                                                const int* __restrict__ tmap,
                                                const float* __restrict__ wt0,
                                                const float* __restrict__ wt1,
                                                const float* __restrict__ biasv,
                                                float* __restrict__ out) {
    const int ent = tmap[blockIdx.x];
    if (ent < 0) return;
    const int e = ent >> 16;
    const int tile_m = (ent & 0xFFFF) * TM;
    const int cnt = counts[e * 16];
    const int tn = blockIdx.y * TN;

    __shared__ u16 lA[TM * BK];   // 8 KB, unpadded [row][32] (global_load_lds layout)
    __shared__ u16 lB[TN * BK];   // 8 KB
    __shared__ int   toks[TM];
    __shared__ float wgt[TM];
    __shared__ float bia[TM];

    const int t  = threadIdx.x;
    const int wv = t >> 6;
    const int l  = t & 63;

    if (t < TM) {
        const int idx = tile_m + t;
        int tok = 0; float w = 0.f, b = 0.f;
        if (idx < cnt) {
            const int entry = lists[e * NTOK + idx];
            tok = entry & 0xFFFF;
            const int slot = entry >> 16;
            w = slot ? wt1[tok] : wt0[tok];
            b = slot ? 0.f : biasv[tok];
        }
        toks[t] = tok; wgt[t] = w; bia[t] = b;
    }
    __syncthreads();

    // staging: chunk c (0..7) covers rows [16c,16c+16); lane l -> row 16c+(l>>2), k (l&3)*8
    const int c0 = wv * 2, c1 = wv * 2 + 1;
    const int rs0 = c0 * 16 + (l >> 2);
    const int rs1 = c1 * 16 + (l >> 2);
    const int koff = (l & 3) * 8;
    const u16* pA0 = x_bf + (size_t)toks[rs0] * HDIM + koff;
    const u16* pA1 = x_bf + (size_t)toks[rs1] * HDIM + koff;
    const u16* pB0 = wt_bf + ((size_t)e << 20) + (size_t)(tn + rs0) * HDIM + koff;
    const u16* pB1 = wt_bf + ((size_t)e << 20) + (size_t)(tn + rs1) * HDIM + koff;
    u16* qA0 = lA + c0 * 512;   // 1 KB chunks, wave-uniform
    u16* qA1 = lA + c1 * 512;
    u16* qB0 = lB + c0 * 512;
    u16* qB1 = lB + c1 * 512;

    // compute: wave -> 64x64 subtile at (wm, wn)
    const int wm = (wv & 1) * 64;
    const int wn = (wv >> 1) * 64;
    const int fm = l & 15;
    const int fk = (l >> 4) * 8;

    float4v acc[4][4];
#pragma unroll
    for (int i = 0; i < 4; i++)
#pragma unroll
        for (int j = 0; j < 4; j++) { float4v z = {0.f, 0.f, 0.f, 0.f}; acc[i][j] = z; }

    for (int k0 = 0; k0 < HDIM; k0 += BK) {
        __syncthreads();                 // prior iteration's ds_reads complete
        gll16(pA0 + k0, qA0);
        gll16(pA1 + k0, qA1);
        gll16(pB0 + k0, qB0);
        gll16(pB1 + k0, qB1);
        __syncthreads();                 // vmcnt drained before barrier

        short8 af[4], bf[4];
#pragma unroll
        for (int mf = 0; mf < 4; mf++)
            af[mf] = *(const short8*)&lA[(wm + mf * 16 + fm) * BK + fk];
#pragma unroll
        for (int nf = 0; nf < 4; nf++)
            bf[nf] = *(const short8*)&lB[(wn + nf * 16 + fm) * BK + fk];
#pragma unroll
        for (int mf = 0; mf < 4; mf++)
#pragma unroll
            for (int nf = 0; nf < 4; nf++)
                acc[mf][nf] = __builtin_amdgcn_mfma_f32_16x16x32_bf16(af[mf], bf[nf], acc[mf][nf], 0, 0, 0);
    }

    // epilogue: out[tok][h] += w * acc + b  (b broadcast over h, nonzero only on slot-0)
#pragma unroll
    for (int mf = 0; mf < 4; mf++) {
#pragma unroll
        for (int r = 0; r < 4; r++) {
            const int m_local = wm + mf * 16 + (l >> 4) * 4 + r;
            if (tile_m + m_local < cnt) {
                const int tok = toks[m_local];
                const float w = wgt[m_local], b = bia[m_local];
#pragma unroll
                for (int nf = 0; nf < 4; nf++) {
                    const int h = tn + wn + nf * 16 + fm;
                    atomicAdd(&out[(size_t)tok * HDIM + h], acc[mf][nf][r] * w + b);
                }
            }
        }
    }
}

extern "C" void kernel_launch(void* const* d_in, const int* in_sizes, int n_in,
                              void* d_out, int out_size, void* d_ws, size_t ws_size,
                              hipStream_t stream) {
    const float* x  = (const float*)d_in[0];   // [4,2048,1024]
    const float* rw = (const float*)d_in[1];   // [8,1024]
    const float* ew = (const float*)d_in[2];   // [8,1024,1024]
    float* out = (float*)d_out;

    char* ws = (char*)d_ws;
    u16*   x_bf   = (u16*)ws;                          // 16 MiB
    u16*   w_bf   = (u16*)(ws + 16777216);             // 16 MiB
    float* wt0    = (float*)(ws + 33554432);           // 32 KiB
    float* wt1    = (float*)(ws + 33587200);           // 32 KiB
    float* biasv  = (float*)(ws + 33619968);           // 32 KiB
    int*   sel    = (int*)(ws + 33652736);             // 32 KiB
    int*   lists  = (int*)(ws + 33685504);             // 256 KiB
    int*   counts = (int*)(ws + 33947648);             // 512 B (8 counters, 64B apart)
    int*   tmap   = (int*)(ws + 33948160);             // 544 B

    hipMemsetAsync(d_out, 0, (size_t)out_size * sizeof(float), stream);
    hipMemsetAsync(counts, 0, NEXP * 16 * sizeof(int), stream);

    prep_w<<<dim3(32, 32, NEXP), 256, 0, stream>>>(ew, w_bf);
    router<<<NTOK / 4, 256, 0, stream>>>(x, rw, x_bf, wt0, wt1, biasv, sel);
    build_lists<<<NTOK / 256, 256, 0, stream>>>(sel, lists, counts);
    plan_tiles<<<1, 64, 0, stream>>>(counts, tmap);
    moe_gemm<<<dim3(MAXT, HDIM / TN, 1), 256, 0, stream>>>(
        x_bf, w_bf, lists, counts, tmap, wt0, wt1, biasv, out);
}

// Round 5
// 200.634 us; speedup vs baseline: 2.1167x; 1.1481x over previous
//
#include <hip/hip_runtime.h>
#include <hip/hip_fp16.h>
#include <cstdint>

typedef unsigned short u16;
typedef __attribute__((ext_vector_type(8))) short short8;
typedef __attribute__((ext_vector_type(4))) float float4v;

#define NTOK 8192
#define HDIM 1024
#define NEXP 8
#define TM 128
#define TN 128
#define BK 64
#define MAXT 136   // max m-tiles over all experts: 16384/128 + 8 rounding partials

__device__ __forceinline__ u16 f2bf(float f) {
    union { float f; uint32_t u; } v; v.f = f;
    uint32_t u = v.u;
    return (u16)((u + 0x7FFFu + ((u >> 16) & 1u)) >> 16);
}

// async global->LDS, 16B per lane; LDS dest = wave-uniform base + lane*16
__device__ __forceinline__ void gll16(const u16* g, u16* l) {
    __builtin_amdgcn_global_load_lds(
        (const __attribute__((address_space(1))) uint32_t*)g,
        (__attribute__((address_space(3))) uint32_t*)l,
        16, 0, 0);
}

// ---------------- W transpose + bf16 quantize: W[e][k][n] -> Wt[e][n][k] ----------------
__global__ __launch_bounds__(256) void prep_w(const float* __restrict__ w,
                                              u16* __restrict__ wt) {
    __shared__ float tile[32][33];
    const int e  = blockIdx.z;
    const int k0 = blockIdx.x * 32;
    const int n0 = blockIdx.y * 32;
    const int r = threadIdx.x >> 3;        // 0..31
    const int c = (threadIdx.x & 7) * 4;   // 0,4,...,28
    const float4 v = *(const float4*)(w + ((size_t)e << 20) + (size_t)(k0 + r) * HDIM + n0 + c);
    tile[r][c] = v.x; tile[r][c+1] = v.y; tile[r][c+2] = v.z; tile[r][c+3] = v.w;
    __syncthreads();
    ushort4 o;
    o.x = f2bf(tile[c][r]); o.y = f2bf(tile[c+1][r]);
    o.z = f2bf(tile[c+2][r]); o.w = f2bf(tile[c+3][r]);
    *(ushort4*)(wt + ((size_t)e << 20) + (size_t)(n0 + r) * HDIM + k0 + c) = o;
}

// ---------------- router: logits, softmax, top-2 -> per-token arrays (NO atomics) ------
__global__ __launch_bounds__(256) void router(const float* __restrict__ x,
                                              const float* __restrict__ rw,
                                              u16* __restrict__ x_bf,
                                              float* __restrict__ wt0,
                                              float* __restrict__ wt1,
                                              float* __restrict__ biasv,
                                              int* __restrict__ sel) {
    const int wv = threadIdx.x >> 6;
    const int l  = threadIdx.x & 63;
    const int n  = blockIdx.x * 4 + wv;  // one wave per token
    const float4* xr = (const float4*)(x + (size_t)n * HDIM);
    ushort4* xo = (ushort4*)(x_bf + (size_t)n * HDIM);

    float4 xv[4];
#pragma unroll
    for (int t = 0; t < 4; t++) {
        xv[t] = xr[t * 64 + l];
        ushort4 p;
        p.x = f2bf(xv[t].x); p.y = f2bf(xv[t].y);
        p.z = f2bf(xv[t].z); p.w = f2bf(xv[t].w);
        xo[t * 64 + l] = p;
    }

    float logits[NEXP];
#pragma unroll
    for (int e = 0; e < NEXP; e++) {
        const float4* rwe = (const float4*)(rw + e * HDIM);
        float acc = 0.f;
#pragma unroll
        for (int t = 0; t < 4; t++) {
            const float4 r = rwe[t * 64 + l];
            acc += xv[t].x * r.x + xv[t].y * r.y + xv[t].z * r.z + xv[t].w * r.w;
        }
#pragma unroll
        for (int s = 32; s > 0; s >>= 1) acc += __shfl_xor(acc, s, 64);
        logits[e] = acc;
    }

    if (l == 0) {
        float mx = logits[0];
#pragma unroll
        for (int e = 1; e < NEXP; e++) mx = fmaxf(mx, logits[e]);
        float p[NEXP]; float sum = 0.f;
#pragma unroll
        for (int e = 0; e < NEXP; e++) { p[e] = expf(logits[e] - mx); sum += p[e]; }
        const float inv = 1.f / sum;
#pragma unroll
        for (int e = 0; e < NEXP; e++) p[e] *= inv;
        int e0 = 0;
#pragma unroll
        for (int e = 1; e < NEXP; e++) if (p[e] > p[e0]) e0 = e;  // ties -> lowest idx (matches top_k)
        int e1 = (e0 == 0) ? 1 : 0;
#pragma unroll
        for (int e = 0; e < NEXP; e++) if (e != e0 && p[e] > p[e1]) e1 = e;
        const float p0 = p[e0], p1 = p[e1];
        const float wsum = p0 + p1 + 1e-6f;
        const float w0 = p0 / wsum, w1 = p1 / wsum;
        wt0[n] = w0; wt1[n] = w1;
        biasv[n] = w0 * p0 + w1 * p1;
        sel[n] = e0 | (e1 << 8);
    }
}

// ---------------- list build: 32 blocks, ballot + 1 atomic per (block,expert) ----------
__global__ __launch_bounds__(256) void build_lists(const int* __restrict__ sel,
                                                   int* __restrict__ lists,
                                                   int* __restrict__ counts) {
    const int n  = blockIdx.x * 256 + threadIdx.x;
    const int wv = threadIdx.x >> 6;
    const int l  = threadIdx.x & 63;
    const int s  = sel[n];
    const int e0 = s & 0xFF, e1 = s >> 8;
    __shared__ int wcnt[NEXP][4];
    __shared__ int ebase[NEXP];
    int pf0 = 0, pf1 = 0;
    const unsigned long long ltmask = (1ULL << l) - 1ULL;
#pragma unroll
    for (int e = 0; e < NEXP; e++) {
        const int slot = (e0 == e) ? 0 : ((e1 == e) ? 1 : -1);
        const unsigned long long bal = __ballot(slot >= 0);
        const int pf = __popcll(bal & ltmask);
        if (slot == 0) pf0 = pf;
        if (slot == 1) pf1 = pf;
        if (l == 0) wcnt[e][wv] = __popcll(bal);
    }
    __syncthreads();
    if (threadIdx.x < NEXP) {
        const int e = threadIdx.x;
        const int tot = wcnt[e][0] + wcnt[e][1] + wcnt[e][2] + wcnt[e][3];
        ebase[e] = atomicAdd(&counts[e * 16], tot);   // counters 64B apart
    }
    __syncthreads();
    int off0 = ebase[e0], off1 = ebase[e1];
#pragma unroll
    for (int i = 0; i < 4; i++) {
        off0 += (i < wv) ? wcnt[e0][i] : 0;
        off1 += (i < wv) ? wcnt[e1][i] : 0;
    }
    lists[e0 * NTOK + off0 + pf0] = n;              // slot 0
    lists[e1 * NTOK + off1 + pf1] = n | 0x10000;    // slot 1
}

// ---------------- tile planner: dense (expert, m-tile) map so the GEMM grid has no holes
__global__ __launch_bounds__(64) void plan_tiles(const int* __restrict__ counts,
                                                 int* __restrict__ tmap) {
    if (threadIdx.x == 0) {
        int idx = 0;
        for (int e = 0; e < NEXP; e++) {
            const int nt = (counts[e * 16] + TM - 1) / TM;
            for (int m = 0; m < nt; m++) tmap[idx++] = (e << 16) | m;
        }
        for (int i = idx; i < MAXT; i++) tmap[i] = -1;
    }
}

// ---------------- grouped GEMM: 128x128 tile, BK=64, swizzled LDS, fp16 stage stores ---
__global__ __launch_bounds__(256) void moe_gemm(const u16* __restrict__ x_bf,
                                                const u16* __restrict__ wt_bf,
                                                const int* __restrict__ lists,
                                                const int* __restrict__ counts,
                                                const int* __restrict__ tmap,
                                                const float* __restrict__ wt0,
                                                const float* __restrict__ wt1,
                                                const float* __restrict__ biasv,
                                                __half* __restrict__ stage0,
                                                __half* __restrict__ stage1) {
    const int ent = tmap[blockIdx.x];
    if (ent < 0) return;
    const int e = ent >> 16;
    const int tile_m = (ent & 0xFFFF) * TM;
    const int cnt = counts[e * 16];
    const int tn = blockIdx.y * TN;

    __shared__ u16 lA[TM * BK];   // 16 KB, [row][64] with k-seg XOR swizzle
    __shared__ u16 lB[TN * BK];   // 16 KB
    __shared__ int   toks[TM];
    __shared__ float wgt[TM];
    __shared__ float bia[TM];
    __shared__ int   slt[TM];

    const int t  = threadIdx.x;
    const int wv = t >> 6;
    const int l  = t & 63;

    if (t < TM) {
        const int idx = tile_m + t;
        int tok = 0; float w = 0.f, b = 0.f; int sl = 0;
        if (idx < cnt) {
            const int entry = lists[e * NTOK + idx];
            tok = entry & 0xFFFF;
            sl = entry >> 16;
            w = sl ? wt1[tok] : wt0[tok];
            b = sl ? 0.f : biasv[tok];
        }
        toks[t] = tok; wgt[t] = w; bia[t] = b; slt[t] = sl;
    }
    __syncthreads();

    // staging: 16 chunks per matrix, chunk c = rows [8c,8c+8); wave handles chunks 4wv..4wv+3
    // lane l -> row 8c+(l>>3); global k-seg = (l&7)^(l>>3) (XOR swizzle), 16B per lane
    const int r_in = l >> 3;                 // 0..7
    const int koff = (((l & 7) ^ r_in)) * 8; // swizzled k offset (u16)
    const u16* pA[4]; const u16* pB[4]; u16* qA[4]; u16* qB[4];
#pragma unroll
    for (int i = 0; i < 4; i++) {
        const int c = wv * 4 + i;
        const int row = c * 8 + r_in;
        pA[i] = x_bf + (size_t)toks[row] * HDIM + koff;
        pB[i] = wt_bf + ((size_t)e << 20) + (size_t)(tn + row) * HDIM + koff;
        qA[i] = lA + c * 512;   // 1 KB chunk, wave-uniform base
        qB[i] = lB + c * 512;
    }

    // compute: wave -> 64x64 subtile at (wm, wn)
    const int wm = (wv & 1) * 64;
    const int wn = (wv >> 1) * 64;
    const int fm = l & 15;
    const int fq = l >> 4;     // 0..3 (k-seg within half)
    // LDS u16 offsets: row*64 + (f ^ (row&7))*8, f = fq (+4 for kh=1 => offset^32)
    int aoff[4], boff[4];
#pragma unroll
    for (int i = 0; i < 4; i++) {
        const int ra = wm + i * 16 + fm;
        const int rb = wn + i * 16 + fm;
        aoff[i] = ra * 64 + ((fq ^ (ra & 7)) * 8);
        boff[i] = rb * 64 + ((fq ^ (rb & 7)) * 8);
    }

    float4v acc[4][4];
#pragma unroll
    for (int i = 0; i < 4; i++)
#pragma unroll
        for (int j = 0; j < 4; j++) { float4v z = {0.f, 0.f, 0.f, 0.f}; acc[i][j] = z; }

    for (int k0 = 0; k0 < HDIM; k0 += BK) {
        __syncthreads();                 // prior iteration's ds_reads complete
#pragma unroll
        for (int i = 0; i < 4; i++) {
            gll16(pA[i] + k0, qA[i]);
            gll16(pB[i] + k0, qB[i]);
        }
        __syncthreads();                 // vmcnt drained before barrier

#pragma unroll
        for (int kh = 0; kh < 2; kh++) {
            short8 af[4], bf[4];
#pragma unroll
            for (int mf = 0; mf < 4; mf++)
                af[mf] = *(const short8*)&lA[aoff[mf] ^ (kh << 5)];
#pragma unroll
            for (int nf = 0; nf < 4; nf++)
                bf[nf] = *(const short8*)&lB[boff[nf] ^ (kh << 5)];
#pragma unroll
            for (int mf = 0; mf < 4; mf++)
#pragma unroll
                for (int nf = 0; nf < 4; nf++)
                    acc[mf][nf] = __builtin_amdgcn_mfma_f32_16x16x32_bf16(af[mf], bf[nf], acc[mf][nf], 0, 0, 0);
        }
    }

    // epilogue: stage[slot][tok][h] = fp16(acc*w + b)  -- plain stores, race-free
#pragma unroll
    for (int mf = 0; mf < 4; mf++) {
#pragma unroll
        for (int r = 0; r < 4; r++) {
            const int m_local = wm + mf * 16 + fq * 4 + r;
            if (tile_m + m_local < cnt) {
                const int tok = toks[m_local];
                const float w = wgt[m_local], b = bia[m_local];
                __half* sp = (slt[m_local] ? stage1 : stage0) + (size_t)tok * HDIM;
#pragma unroll
                for (int nf = 0; nf < 4; nf++) {
                    const int h = tn + wn + nf * 16 + fm;
                    sp[h] = __float2half(acc[mf][nf][r] * w + b);
                }
            }
        }
    }
}

// ---------------- combine: out = stage0 + stage1 (fully coalesced) ----------------
__global__ __launch_bounds__(256) void combine(const __half* __restrict__ s0,
                                               const __half* __restrict__ s1,
                                               float* __restrict__ out) {
    const size_t idx = ((size_t)blockIdx.x * 256 + threadIdx.x) * 8;
    union { uint4 v; __half h[8]; } a, b;
    a.v = *(const uint4*)(s0 + idx);
    b.v = *(const uint4*)(s1 + idx);
    float4 o0, o1;
    o0.x = __half2float(a.h[0]) + __half2float(b.h[0]);
    o0.y = __half2float(a.h[1]) + __half2float(b.h[1]);
    o0.z = __half2float(a.h[2]) + __half2float(b.h[2]);
    o0.w = __half2float(a.h[3]) + __half2float(b.h[3]);
    o1.x = __half2float(a.h[4]) + __half2float(b.h[4]);
    o1.y = __half2float(a.h[5]) + __half2float(b.h[5]);
    o1.z = __half2float(a.h[6]) + __half2float(b.h[6]);
    o1.w = __half2float(a.h[7]) + __half2float(b.h[7]);
    *(float4*)(out + idx)     = o0;
    *(float4*)(out + idx + 4) = o1;
}

extern "C" void kernel_launch(void* const* d_in, const int* in_sizes, int n_in,
                              void* d_out, int out_size, void* d_ws, size_t ws_size,
                              hipStream_t stream) {
    const float* x  = (const float*)d_in[0];   // [4,2048,1024]
    const float* rw = (const float*)d_in[1];   // [8,1024]
    const float* ew = (const float*)d_in[2];   // [8,1024,1024]
    float* out = (float*)d_out;

    char* ws = (char*)d_ws;
    u16*    x_bf   = (u16*)ws;                          // 16 MiB
    u16*    w_bf   = (u16*)(ws + 16777216);             // 16 MiB
    __half* stage0 = (__half*)(ws + 33554432);          // 16 MiB
    __half* stage1 = (__half*)(ws + 50331648);          // 16 MiB
    float*  wt0    = (float*)(ws + 67108864);           // 32 KiB
    float*  wt1    = (float*)(ws + 67141632);           // 32 KiB
    float*  biasv  = (float*)(ws + 67174400);           // 32 KiB
    int*    sel    = (int*)(ws + 67207168);             // 32 KiB
    int*    lists  = (int*)(ws + 67239936);             // 256 KiB
    int*    counts = (int*)(ws + 67502080);             // 512 B (8 counters, 64B apart)
    int*    tmap   = (int*)(ws + 67502592);             // 544 B

    hipMemsetAsync(counts, 0, NEXP * 16 * sizeof(int), stream);

    prep_w<<<dim3(32, 32, NEXP), 256, 0, stream>>>(ew, w_bf);
    router<<<NTOK / 4, 256, 0, stream>>>(x, rw, x_bf, wt0, wt1, biasv, sel);
    build_lists<<<NTOK / 256, 256, 0, stream>>>(sel, lists, counts);
    plan_tiles<<<1, 64, 0, stream>>>(counts, tmap);
    moe_gemm<<<dim3(MAXT, HDIM / TN, 1), 256, 0, stream>>>(
        x_bf, w_bf, lists, counts, tmap, wt0, wt1, biasv, stage0, stage1);
    combine<<<(NTOK * HDIM) / (256 * 8), 256, 0, stream>>>(stage0, stage1, out);
}